// Round 17
// baseline (77.496 us; speedup 1.0000x reference)
//
#include <hip/hip_runtime.h>

typedef __attribute__((ext_vector_type(4))) float f32x4;
typedef __attribute__((ext_vector_type(8))) short bf16x8;

__device__ __forceinline__ short bf16_rne(float f) {
    unsigned int u = __float_as_uint(f);
    u += 0x7FFFu + ((u >> 16) & 1u);
    return (short)(u >> 16);
}

// G=16, in_g=out_g=64. rows-per-group = 32768, total rows = 524288.
// Row r: 64 contiguous floats of x; group g = r>>15.
// out[(g*64+o)*32768 + (r & 32767)].
// PERSISTENT wave, FAR chunks, SIMPLE loop (R17 = R11 structure + R16 mapping):
// wave w handles chunks c0 and c0+256 of group g (64 KB apart per channel row
// -> granule-independent; R11's adjacent chunks re-amplified WRITE 150->210,
// R16's far chunks measured clean 152). R16's unified prefetch indexing cost
// VGPR 108 / occupancy 19%; R11's duplicated simple loop measured VGPR 84.
// 4096 waves = 1024 blocks x 4; one W/gamma/beta preamble per 2 chunks.
// NUMERICS: R1's validated path (absmax 0.031): A = bf16(xhat*gamma+beta),
// B = bf16(W), bias in fp32 epilogue.
// STORES (R10-verified, FROZEN): per chunk, defer 4 tiles in vout; per channel
// store its FULL 256-B span in 4 back-to-back nt stores. Cross-chunk prefetch
// issues BEFORE chunk-0's store burst. R13/R14: 2-deep prefetch regresses.

__global__ __launch_bounds__(256, 3)
void gln_mfma_kernel(const float* __restrict__ x,
                     const float* __restrict__ gamma,
                     const float* __restrict__ beta,
                     const float* __restrict__ W,
                     const float* __restrict__ bias,
                     float* __restrict__ out)
{
    const int tid  = threadIdx.x;
    const int lane = tid & 63;
    const int w    = blockIdx.x * 4 + (tid >> 6);   // 0..4095
    const int g    = w >> 8;                         // 16 groups, 256 waves each
    const int c0   = w & 255;                        // chunk-0 id in group
    const int rr0_0 = c0 << 6;                       // chunk-0 row base
    const int rr0_1 = rr0_0 + 16384;                 // chunk-1 row base (far)

    const int l15 = lane & 15;
    const int l4  = lane >> 4;      // 0..3
    const int ks  = l4 * 8;         // k-slice base within a 32-wide K chunk

    const float* xg = x   + (size_t)g * 32768 * 64;
    float* outg     = out + (size_t)g * 64 * 32768;

    // ---- B fragments: lane elem j = W[g][ot*16+l15][kc*32+ks+j] ----
    bf16x8 bfrag[4][2];
    {
        const float* Wg = W + (size_t)(g * 64) * 64;
        #pragma unroll
        for (int ot = 0; ot < 4; ++ot) {
            const float* wrow = Wg + (size_t)(ot * 16 + l15) * 64;
            #pragma unroll
            for (int kc = 0; kc < 2; ++kc) {
                f32x4 w0 = *(const f32x4*)(wrow + kc * 32 + ks);
                f32x4 w1 = *(const f32x4*)(wrow + kc * 32 + ks + 4);
                bf16x8 f;
                #pragma unroll
                for (int j = 0; j < 4; ++j) { f[j] = bf16_rne(w0[j]); f[j + 4] = bf16_rne(w1[j]); }
                bfrag[ot][kc] = f;
            }
        }
    }

    // ---- gamma/beta for this lane's 16 k positions ----
    float gk[16], bk[16];
    {
        const float* gp = gamma + g * 64;
        const float* bp = beta  + g * 64;
        #pragma unroll
        for (int kc = 0; kc < 2; ++kc) {
            f32x4 g0 = *(const f32x4*)(gp + kc * 32 + ks);
            f32x4 g1 = *(const f32x4*)(gp + kc * 32 + ks + 4);
            f32x4 b0 = *(const f32x4*)(bp + kc * 32 + ks);
            f32x4 b1 = *(const f32x4*)(bp + kc * 32 + ks + 4);
            #pragma unroll
            for (int j = 0; j < 4; ++j) {
                gk[kc * 8 + j] = g0[j]; gk[kc * 8 + 4 + j] = g1[j];
                bk[kc * 8 + j] = b0[j]; bk[kc * 8 + 4 + j] = b1[j];
            }
        }
    }

    float bo[4];
    #pragma unroll
    for (int ot = 0; ot < 4; ++ot) bo[ot] = bias[g * 64 + ot * 16 + l15];

    // ---- persistent loop: 2 far chunks x 4 tiles, 1-deep prefetch ----
    f32x4 buf[2][4];
    {
        const float* rowp = xg + (size_t)(rr0_0 + l15) * 64;
        buf[0][0] = *(const f32x4*)(rowp + ks);
        buf[0][1] = *(const f32x4*)(rowp + ks + 4);
        buf[0][2] = *(const f32x4*)(rowp + 32 + ks);
        buf[0][3] = *(const f32x4*)(rowp + 32 + ks + 4);
    }

    #pragma unroll
    for (int c = 0; c < 2; ++c) {
        const int rr0 = c ? rr0_1 : rr0_0;
        f32x4 vout[4][4];               // [tile][ot] — stores deferred per chunk

        #pragma unroll
        for (int t = 0; t < 4; ++t) {
            // prefetch next tile in chunk, or chunk-1 tile-0 (before the
            // chunk-0 store burst; simple R11-style expression keeps VGPR low)
            const int pf = (t < 3) ? (rr0 + (t + 1) * 16)
                                   : ((c == 0) ? rr0_1 : -1);
            if (pf >= 0) {
                const float* rowp = xg + (size_t)(pf + l15) * 64;
                buf[(t + 1) & 1][0] = *(const f32x4*)(rowp + ks);
                buf[(t + 1) & 1][1] = *(const f32x4*)(rowp + ks + 4);
                buf[(t + 1) & 1][2] = *(const f32x4*)(rowp + 32 + ks);
                buf[(t + 1) & 1][3] = *(const f32x4*)(rowp + 32 + ks + 4);
            }

            // LN stats over the row (4 lanes share a row: xor 16, 32)
            float s = 0.f, s2 = 0.f;
            #pragma unroll
            for (int i = 0; i < 4; ++i) {
                #pragma unroll
                for (int j = 0; j < 4; ++j) {
                    float v = buf[t & 1][i][j];
                    s += v; s2 += v * v;
                }
            }
            s  += __shfl_xor(s, 16, 64);  s  += __shfl_xor(s, 32, 64);
            s2 += __shfl_xor(s2, 16, 64); s2 += __shfl_xor(s2, 32, 64);
            const float mu   = s * (1.0f / 64.0f);
            const float var  = s2 * (1.0f / 64.0f) - mu * mu;
            const float rstd = rsqrtf(var + 1e-6f);

            // normalize + affine -> A fragments (bf16)   [R1 numerics]
            bf16x8 a0, a1;
            #pragma unroll
            for (int j = 0; j < 8; ++j) {
                float c1 = rstd * gk[j];
                float v  = buf[t & 1][j >> 2][j & 3] * c1 + (bk[j] - mu * c1);
                a0[j] = bf16_rne(v);
            }
            #pragma unroll
            for (int j = 0; j < 8; ++j) {
                float c1 = rstd * gk[8 + j];
                float v  = buf[t & 1][2 + (j >> 2)][j & 3] * c1 + (bk[8 + j] - mu * c1);
                a1[j] = bf16_rne(v);
            }

            #pragma unroll
            for (int ot = 0; ot < 4; ++ot) {
                f32x4 acc = {0.f, 0.f, 0.f, 0.f};
                acc = __builtin_amdgcn_mfma_f32_16x16x32_bf16(a0, bfrag[ot][0], acc, 0, 0, 0);
                acc = __builtin_amdgcn_mfma_f32_16x16x32_bf16(a1, bfrag[ot][1], acc, 0, 0, 0);
                #pragma unroll
                for (int q = 0; q < 4; ++q) acc[q] += bo[ot];
                vout[t][ot] = acc;
            }
        }

        // ---- chunk epilogue: per channel, FULL 256 B span, 4 adjacent nt stores ----
        #pragma unroll
        for (int ot = 0; ot < 4; ++ot) {
            float* base = outg + (size_t)(ot * 16 + l15) * 32768 + rr0 + l4 * 4;
            #pragma unroll
            for (int t = 0; t < 4; ++t) {
                __builtin_nontemporal_store(vout[t][ot], (f32x4*)(base + t * 16));
            }
        }
    }
}

extern "C" void kernel_launch(void* const* d_in, const int* in_sizes, int n_in,
                              void* d_out, int out_size, void* d_ws, size_t ws_size,
                              hipStream_t stream) {
    const float* x     = (const float*)d_in[0];
    const float* gamma = (const float*)d_in[1];
    const float* beta  = (const float*)d_in[2];
    const float* W     = (const float*)d_in[3];
    const float* b     = (const float*)d_in[4];
    float* out = (float*)d_out;

    dim3 grid(1024), block(256);
    hipLaunchKernelGGL(gln_mfma_kernel, grid, block, 0, stream, x, gamma, beta, W, b, out);
}

// Round 18
// 53.602 us; speedup vs baseline: 1.4458x; 1.4458x over previous
//
#include <hip/hip_runtime.h>

typedef __attribute__((ext_vector_type(4))) float f32x4;
typedef __attribute__((ext_vector_type(8))) short bf16x8;

__device__ __forceinline__ short bf16_rne(float f) {
    unsigned int u = __float_as_uint(f);
    u += 0x7FFFu + ((u >> 16) & 1u);
    return (short)(u >> 16);
}

// G=16, in_g=out_g=64. rows-per-group = 32768, total rows = 524288.
// Row r: 64 contiguous floats of x; group g = r>>15.
// out[(g*64+o)*32768 + (r & 32767)].
// Wave: 64 consecutive rows = 4 tiles of 16 rows. 8192 waves = 2048 blocks x 4.
// == EXACT R10 STRUCTURE (champion, 61.2us) except store flags. ==
// NUMERICS: R1's validated path (absmax 0.031): A = bf16(xhat*gamma+beta),
// B = bf16(W), bias in fp32 epilogue.
// STORES (R10-verified, FROZEN): defer all 4 tiles in vout regs; per channel
// store its FULL 256-B span in 4 back-to-back stores at wave end.
// R18 change: stores emitted as inline asm `global_store_dwordx4 ... sc1 nt`.
// Theory: warm FETCH is pinned at 66.7 MB = half of x because the out stream
// ALLOCATES in L3 (nt only streams L2; sc1 governs MALL) and evicts half of
// x (134 MB) each replay. sc1+nt -> out bypasses L3 -> x fully L3-resident.
// FAILED AVENUES (do not retry): persistence in any form (R11 adjacent=210MB,
// R16 unified-idx=VGPR108, R17 simple+bounds3=207MB WRITE + 98MB FETCH —
// store-burst concurrency re-amplifies writes); 2-deep prefetch (R13/R14);
// channel-split waves (R15); LDS-staged epilogue (R8).

__global__ __launch_bounds__(256, 2)
void gln_mfma_kernel(const float* __restrict__ x,
                     const float* __restrict__ gamma,
                     const float* __restrict__ beta,
                     const float* __restrict__ W,
                     const float* __restrict__ bias,
                     float* __restrict__ out)
{
    const int tid  = threadIdx.x;
    const int lane = tid & 63;
    const int w    = blockIdx.x * 4 + (tid >> 6);   // 0..8191
    const int g    = w >> 9;                         // 16 groups, 512 waves each
    const int rr0  = (w & 511) << 6;                 // row-in-group base (64 rows)

    const int l15 = lane & 15;
    const int l4  = lane >> 4;      // 0..3
    const int ks  = l4 * 8;         // k-slice base within a 32-wide K chunk

    // ---- B fragments: lane elem j = W[g][ot*16+l15][kc*32+ks+j] ----
    bf16x8 bfrag[4][2];
    {
        const float* Wg = W + (size_t)(g * 64) * 64;
        #pragma unroll
        for (int ot = 0; ot < 4; ++ot) {
            const float* wrow = Wg + (size_t)(ot * 16 + l15) * 64;
            #pragma unroll
            for (int kc = 0; kc < 2; ++kc) {
                f32x4 w0 = *(const f32x4*)(wrow + kc * 32 + ks);
                f32x4 w1 = *(const f32x4*)(wrow + kc * 32 + ks + 4);
                bf16x8 f;
                #pragma unroll
                for (int j = 0; j < 4; ++j) { f[j] = bf16_rne(w0[j]); f[j + 4] = bf16_rne(w1[j]); }
                bfrag[ot][kc] = f;
            }
        }
    }

    // ---- gamma/beta for this lane's 16 k positions ----
    float gk[16], bk[16];
    {
        const float* gp = gamma + g * 64;
        const float* bp = beta  + g * 64;
        #pragma unroll
        for (int kc = 0; kc < 2; ++kc) {
            f32x4 g0 = *(const f32x4*)(gp + kc * 32 + ks);
            f32x4 g1 = *(const f32x4*)(gp + kc * 32 + ks + 4);
            f32x4 b0 = *(const f32x4*)(bp + kc * 32 + ks);
            f32x4 b1 = *(const f32x4*)(bp + kc * 32 + ks + 4);
            #pragma unroll
            for (int j = 0; j < 4; ++j) {
                gk[kc * 8 + j] = g0[j]; gk[kc * 8 + 4 + j] = g1[j];
                bk[kc * 8 + j] = b0[j]; bk[kc * 8 + 4 + j] = b1[j];
            }
        }
    }

    float bo[4];
    #pragma unroll
    for (int ot = 0; ot < 4; ++ot) bo[ot] = bias[g * 64 + ot * 16 + l15];

    const float* xg = x   + (size_t)g * 32768 * 64;
    float* outg     = out + (size_t)g * 64 * 32768;

    // ---- main loop: 4 tiles of 16 rows, register double-buffered ----
    f32x4 buf[2][4];
    {
        const float* rowp = xg + (size_t)(rr0 + l15) * 64;
        buf[0][0] = *(const f32x4*)(rowp + ks);
        buf[0][1] = *(const f32x4*)(rowp + ks + 4);
        buf[0][2] = *(const f32x4*)(rowp + 32 + ks);
        buf[0][3] = *(const f32x4*)(rowp + 32 + ks + 4);
    }

    f32x4 vout[4][4];                   // [tile][ot] — all stores deferred

    #pragma unroll
    for (int t = 0; t < 4; ++t) {
        if (t + 1 < 4) {
            const float* rowp = xg + (size_t)(rr0 + (t + 1) * 16 + l15) * 64;
            buf[(t + 1) & 1][0] = *(const f32x4*)(rowp + ks);
            buf[(t + 1) & 1][1] = *(const f32x4*)(rowp + ks + 4);
            buf[(t + 1) & 1][2] = *(const f32x4*)(rowp + 32 + ks);
            buf[(t + 1) & 1][3] = *(const f32x4*)(rowp + 32 + ks + 4);
        }

        // LN stats over the row (4 lanes share a row: xor 16, 32)
        float s = 0.f, s2 = 0.f;
        #pragma unroll
        for (int i = 0; i < 4; ++i) {
            #pragma unroll
            for (int j = 0; j < 4; ++j) {
                float v = buf[t & 1][i][j];
                s += v; s2 += v * v;
            }
        }
        s  += __shfl_xor(s, 16, 64);  s  += __shfl_xor(s, 32, 64);
        s2 += __shfl_xor(s2, 16, 64); s2 += __shfl_xor(s2, 32, 64);
        const float mu   = s * (1.0f / 64.0f);
        const float var  = s2 * (1.0f / 64.0f) - mu * mu;
        const float rstd = rsqrtf(var + 1e-6f);

        // normalize + affine -> A fragments (bf16)   [R1 numerics]
        bf16x8 a0, a1;
        #pragma unroll
        for (int j = 0; j < 8; ++j) {
            float c1 = rstd * gk[j];
            float v  = buf[t & 1][j >> 2][j & 3] * c1 + (bk[j] - mu * c1);
            a0[j] = bf16_rne(v);
        }
        #pragma unroll
        for (int j = 0; j < 8; ++j) {
            float c1 = rstd * gk[8 + j];
            float v  = buf[t & 1][2 + (j >> 2)][j & 3] * c1 + (bk[8 + j] - mu * c1);
            a1[j] = bf16_rne(v);
        }

        #pragma unroll
        for (int ot = 0; ot < 4; ++ot) {
            f32x4 acc = {0.f, 0.f, 0.f, 0.f};
            acc = __builtin_amdgcn_mfma_f32_16x16x32_bf16(a0, bfrag[ot][0], acc, 0, 0, 0);
            acc = __builtin_amdgcn_mfma_f32_16x16x32_bf16(a1, bfrag[ot][1], acc, 0, 0, 0);
            #pragma unroll
            for (int q = 0; q < 4; ++q) acc[q] += bo[ot];
            vout[t][ot] = acc;
        }
    }

    // ---- epilogue: per channel, FULL 256 B span, 4 adjacent stores,
    //      sc1+nt -> stream past L2 AND bypass L3 (MALL) allocation ----
    #pragma unroll
    for (int ot = 0; ot < 4; ++ot) {
        float* base = outg + (size_t)(ot * 16 + l15) * 32768 + rr0 + l4 * 4;
        #pragma unroll
        for (int t = 0; t < 4; ++t) {
            float* dst = base + t * 16;
            asm volatile("global_store_dwordx4 %0, %1, off sc1 nt"
                         :: "v"(dst), "v"(vout[t][ot]) : "memory");
        }
    }
}

extern "C" void kernel_launch(void* const* d_in, const int* in_sizes, int n_in,
                              void* d_out, int out_size, void* d_ws, size_t ws_size,
                              hipStream_t stream) {
    const float* x     = (const float*)d_in[0];
    const float* gamma = (const float*)d_in[1];
    const float* beta  = (const float*)d_in[2];
    const float* W     = (const float*)d_in[3];
    const float* b     = (const float*)d_in[4];
    float* out = (float*)d_out;

    dim3 grid(2048), block(256);
    hipLaunchKernelGGL(gln_mfma_kernel, grid, block, 0, stream, x, gamma, beta, W, b, out);
}